// Round 9
// baseline (320.706 us; speedup 1.0000x reference)
//
#include <hip/hip_runtime.h>
#include <hip/hip_bf16.h>
#include <float.h>
#include <stdint.h>

#define NPT    4096
#define EMB    512
#define NH     8
#define HD     64
#define KSPLIT 32     // score k-range split: KRANGE = 128 (4 tiles of 32)

typedef __attribute__((ext_vector_type(8))) short bf16x8;
typedef __attribute__((ext_vector_type(4))) float f32x4;
typedef __attribute__((ext_vector_type(16))) float f32x16;
typedef uint32_t u32;

// async global->LDS DMA, 16B/lane. LDS dest = wave-uniform base + lane*16.
__device__ __forceinline__ void async_ld16(const void* gsrc, void* ldst) {
    __builtin_amdgcn_global_load_lds(
        (const __attribute__((address_space(1))) u32*)gsrc,
        (__attribute__((address_space(3))) u32*)ldst, 16, 0, 0);
}

// exact 3-way bf16 split of f32 (hi+mid+lo covers all 24 mantissa bits)
__device__ __forceinline__ void split3(float a, unsigned short& h,
                                       unsigned short& m, unsigned short& l) {
    __hip_bfloat16 bh = __float2bfloat16(a);
    float fh = __bfloat162float(bh);
    float r1 = a - fh;
    __hip_bfloat16 bm = __float2bfloat16(r1);
    float fm = __bfloat162float(bm);
    float r2 = r1 - fm;
    __hip_bfloat16 bl = __float2bfloat16(r2);
    h = *reinterpret_cast<unsigned short*>(&bh);
    m = *reinterpret_cast<unsigned short*>(&bm);
    l = *reinterpret_cast<unsigned short*>(&bl);
}

// ---------------------------------------------------------------------------
// 1) pack adj into bitmask [N][N/32]
// ---------------------------------------------------------------------------
__global__ __launch_bounds__(256) void pack_adj_kernel(const int* __restrict__ adj,
                                                       unsigned* __restrict__ bits) {
    int gid = blockIdx.x * 256 + threadIdx.x;
    int q = gid >> 7;
    int w = gid & 127;
    const int4* p = (const int4*)(adj + (size_t)q * NPT + w * 32);
    unsigned m = 0;
#pragma unroll
    for (int i = 0; i < 8; ++i) {
        int4 v = p[i];
        m |= (v.x != 0 ? 1u : 0u) << (i * 4 + 0);
        m |= (v.y != 0 ? 1u : 0u) << (i * 4 + 1);
        m |= (v.z != 0 ? 1u : 0u) << (i * 4 + 2);
        m |= (v.w != 0 ? 1u : 0u) << (i * 4 + 3);
    }
    bits[gid] = m;
}

// ---------------------------------------------------------------------------
// 2) split into 3 bf16 planes. x -> flat [p][n][k]. W -> granule-major tiles
//    [p][ebk(8)][kc(16)][g(4)][e_local(64)][8 shorts]
// ---------------------------------------------------------------------------
__global__ __launch_bounds__(256) void split_planes(const float* __restrict__ x,
                                                    const float* __restrict__ wq,
                                                    const float* __restrict__ wk,
                                                    const float* __restrict__ wv,
                                                    unsigned short* __restrict__ xs,
                                                    unsigned short* __restrict__ wqs,
                                                    unsigned short* __restrict__ wks,
                                                    unsigned short* __restrict__ wvs) {
    int y = blockIdx.y;
    size_t i = (size_t)blockIdx.x * 256 + threadIdx.x;
    if (y == 0) {
        const size_t PL = (size_t)NPT * EMB;
        float4 v = ((const float4*)x)[i];
        ushort4 h, m, l;
        split3(v.x, h.x, m.x, l.x);
        split3(v.y, h.y, m.y, l.y);
        split3(v.z, h.z, m.z, l.z);
        split3(v.w, h.w, m.w, l.w);
        ((ushort4*)xs)[i]            = h;
        ((ushort4*)(xs + PL))[i]     = m;
        ((ushort4*)(xs + 2 * PL))[i] = l;
    } else {
        const size_t WPL = 262144;
        if (i >= WPL / 4) return;
        const float* src = (y == 1) ? wq : (y == 2) ? wk : wv;
        unsigned short* dst = (y == 1) ? wqs : (y == 2) ? wks : wvs;
        float4 v = ((const float4*)src)[i];
        int e  = (int)(i >> 7);
        int k0 = ((int)i & 127) * 4;
        int ebk = e >> 6, el = e & 63;
        int kc = k0 >> 5, g = (k0 >> 3) & 3, dd = k0 & 7;
        size_t off = ((((size_t)ebk * 16 + kc) * 4 + g) * 64 + el) * 8 + dd;
        ushort4 h, m, l;
        split3(v.x, h.x, m.x, l.x);
        split3(v.y, h.y, m.y, l.y);
        split3(v.z, h.z, m.z, l.z);
        split3(v.w, h.w, m.w, l.w);
        *(ushort4*)(dst + off)           = h;
        *(ushort4*)(dst + WPL + off)     = m;
        *(ushort4*)(dst + 2 * WPL + off) = l;
    }
}

// ---------------------------------------------------------------------------
// 3) projections via split-bf16 MFMA (unchanged from R8 — clean win there).
// ---------------------------------------------------------------------------
__global__ __launch_bounds__(256) void gemm_mfma(const unsigned short* __restrict__ xs,
                                                 const unsigned short* __restrict__ wqs,
                                                 const unsigned short* __restrict__ wks,
                                                 const unsigned short* __restrict__ wvs,
                                                 unsigned short* __restrict__ Q3,
                                                 unsigned short* __restrict__ K3,
                                                 float* __restrict__ V) {
    const int z = blockIdx.z;
    const unsigned short* W3 = (z == 0) ? wqs : (z == 1) ? wks : wvs;
    const size_t XPL = (size_t)NPT * EMB;
    const size_t WPL = 262144;
    const size_t OPL = (size_t)NH * NPT * HD;

    const int nb = blockIdx.x * 128;
    const int ebk = blockIdx.y;
    const int tid = threadIdx.x;
    const int wv = tid >> 6, lane = tid & 63;
    const int m = lane & 15, quad = lane >> 4;
    const int n0 = nb + wv * 32;

    __shared__ __align__(16) unsigned short Ws[2][3 * 2048];

    auto prefetchW = [&](int kc, int buf) {
#pragma unroll
        for (int i2 = 0; i2 < 3; ++i2) {
            int c = wv + 4 * i2;
            int p = c >> 2, sub = c & 3;
            const unsigned short* src = W3 + (size_t)p * WPL
                + ((size_t)ebk * 16 + kc) * 2048 + (sub * 64 + lane) * 8;
            async_ld16(src, &Ws[buf][p * 2048 + sub * 512]);
        }
    };
    bf16x8 bfA[2][3], bfB[2][3];
    auto load_bf = [&](bf16x8 (&bf)[2][3], int kc) {
#pragma unroll
        for (int nt = 0; nt < 2; ++nt)
#pragma unroll
            for (int p = 0; p < 3; ++p)
                bf[nt][p] = *(const bf16x8*)(xs + (size_t)p * XPL
                    + (size_t)(n0 + nt * 16 + m) * EMB + kc * 32 + quad * 8);
    };

    f32x4 acc[4][2];
#pragma unroll
    for (int mt = 0; mt < 4; ++mt)
#pragma unroll
        for (int nt = 0; nt < 2; ++nt) acc[mt][nt] = (f32x4){0.f, 0.f, 0.f, 0.f};

    prefetchW(0, 0);
    load_bf(bfA, 0);

    auto iter = [&](int kc, int buf, bf16x8 (&cur)[2][3], bf16x8 (&nxt)[2][3]) {
        __syncthreads();
        if (kc < 15) { prefetchW(kc + 1, buf ^ 1); load_bf(nxt, kc + 1); }
#pragma unroll
        for (int ga = 0; ga < 3; ++ga) {
            bf16x8 af[4];
#pragma unroll
            for (int mt = 0; mt < 4; ++mt)
                af[mt] = *(const bf16x8*)&Ws[buf][ga * 2048 + (quad * 64 + mt * 16 + m) * 8];
#pragma unroll
            for (int pb = 0; pb < 3 - ga; ++pb)
#pragma unroll
                for (int mt = 0; mt < 4; ++mt)
#pragma unroll
                    for (int nt = 0; nt < 2; ++nt)
                        acc[mt][nt] = __builtin_amdgcn_mfma_f32_16x16x32_bf16(
                            af[mt], cur[nt][pb], acc[mt][nt], 0, 0, 0);
        }
    };

#pragma unroll 1
    for (int kc2 = 0; kc2 < 16; kc2 += 2) {
        iter(kc2, 0, bfA, bfB);
        iter(kc2 + 1, 1, bfB, bfA);
    }

    const int h = ebk;
#pragma unroll
    for (int mt = 0; mt < 4; ++mt)
#pragma unroll
        for (int nt = 0; nt < 2; ++nt) {
            const int n = n0 + nt * 16 + m;
            const int d0 = mt * 16 + quad * 4;
            f32x4 a = acc[mt][nt];
            if (z == 2) {
                *(f32x4*)(V + (size_t)n * EMB + ebk * 64 + d0) = a;
            } else {
                ushort4 ph, pm, pl;
                split3(a[0], ph.x, pm.x, pl.x);
                split3(a[1], ph.y, pm.y, pl.y);
                split3(a[2], ph.z, pm.z, pl.z);
                split3(a[3], ph.w, pm.w, pl.w);
                if (z == 0) {              // Q3 flat [p][h][n][d]
                    size_t base = ((size_t)h * NPT + n) * HD + d0;
                    *(ushort4*)(Q3 + base)           = ph;
                    *(ushort4*)(Q3 + OPL + base)     = pm;
                    *(ushort4*)(Q3 + 2 * OPL + base) = pl;
                } else {                   // K3 granule-major [p][h][kt][dg][kk][8]
                    int kt = n >> 5, kk = n & 31, g = d0 >> 3, dd = d0 & 7;
                    size_t off = ((size_t)h * 128 + kt) * 2048 + g * 256 + kk * 8 + dd;
                    *(ushort4*)(K3 + off)           = ph;
                    *(ushort4*)(K3 + OPL + off)     = pm;
                    *(ushort4*)(K3 + 2 * OPL + off) = pl;
                }
            }
        }
}

// ---------------------------------------------------------------------------
// 4) masked argmax via bf16x3 MFMA, 32x32x16 shape. 2-wave blocks (64q),
//    2048 blocks -> 6 resident + backfill per CU. K tile 32k x 64d x 3p
//    (12 KB) double-buffered via global_load_lds. One q per lane in C layout
//    -> scalar best tracking, one bits word/tile, single shfl step.
// ---------------------------------------------------------------------------
__global__ __launch_bounds__(128) void score_mfma(const unsigned short* __restrict__ Q3,
                                                  const unsigned short* __restrict__ K3,
                                                  const unsigned* __restrict__ bits,
                                                  float* __restrict__ pval,
                                                  int* __restrict__ pidx) {
    const int qb = blockIdx.x * 64;        // x fastest: qb%8 XCD locality for Q3
    const int ks = blockIdx.y;             // 0..KSPLIT-1, KRANGE=128 (4 tiles)
    const int tid = threadIdx.x;
    const int wv = tid >> 6, lane = tid & 63;
    const int col = lane & 31, hi = lane >> 5;
    const size_t PL = (size_t)NH * NPT * HD;
    const int kq = qb + wv * 32;
    const int q = kq + col;                // this lane's q (C col = lane&31)

    __shared__ __align__(16) unsigned short Ks[2][3 * 2048];   // 2 x 12 KB

    auto prefetchK = [&](int h, int kst, int buf) {
        int kt = ks * 4 + kst;
#pragma unroll
        for (int i2 = 0; i2 < 6; ++i2) {   // 12 chunks of 1 KB, 6 per wave
            int c = wv + 2 * i2;
            int p = c >> 2, dgp = c & 3;
            const unsigned short* src = K3 + (size_t)p * PL
                + ((size_t)h * 128 + kt) * 2048 + dgp * 512 + lane * 8;
            async_ld16(src, &Ks[buf][p * 2048 + dgp * 512]);
        }
    };

    prefetchK(0, 0, 0);

    bf16x8 qf[4][3];                       // [dc][plane], 48 VGPR, per-head
    float bestv = -FLT_MAX; int besti = 0;

#pragma unroll 1
    for (int h = 0; h < NH; ++h) {
#pragma unroll
        for (int kst = 0; kst < 4; ++kst) {
            const int t = h * 4 + kst;
            const int buf = t & 1;
            const int kbase = ks * 128 + kst * 32;
            __syncthreads();               // Ks[buf] staged & visible
            if (t < NH * 4 - 1) prefetchK((t + 1) >> 2, (t + 1) & 3, buf ^ 1);

            if (kst == 0) {                // B-frag: n=lane&31, k=hi*8+j; d=dc*16+hi*8+j
#pragma unroll
                for (int dc = 0; dc < 4; ++dc)
#pragma unroll
                    for (int p = 0; p < 3; ++p)
                        qf[dc][p] = *(const bf16x8*)(Q3 + (size_t)p * PL
                            + ((size_t)h * NPT + q) * HD + dc * 16 + hi * 8);
                bestv = -FLT_MAX; besti = 0;
            }

            unsigned w = bits[(size_t)q * (NPT / 32) + (kbase >> 5)];
            unsigned wsh = w >> (hi * 4);

            // two independent accumulator chains (dc 0-1 / dc 2-3)
            f32x16 acca, accb;
#pragma unroll
            for (int r = 0; r < 16; ++r) { acca[r] = 0.f; accb[r] = 0.f; }

#pragma unroll
            for (int ga = 0; ga < 3; ++ga) {
                bf16x8 kf[4];              // A-frag: m=lane&31=kk, k=hi*8+j
#pragma unroll
                for (int dc = 0; dc < 4; ++dc)
                    kf[dc] = *(const bf16x8*)
                        &Ks[buf][ga * 2048 + (dc * 2 + hi) * 256 + col * 8];
#pragma unroll
                for (int pb = 0; pb < 3 - ga; ++pb) {
                    acca = __builtin_amdgcn_mfma_f32_32x32x16_bf16(kf[0], qf[0][pb], acca, 0, 0, 0);
                    accb = __builtin_amdgcn_mfma_f32_32x32x16_bf16(kf[2], qf[2][pb], accb, 0, 0, 0);
                    acca = __builtin_amdgcn_mfma_f32_32x32x16_bf16(kf[1], qf[1][pb], acca, 0, 0, 0);
                    accb = __builtin_amdgcn_mfma_f32_32x32x16_bf16(kf[3], qf[3][pb], accb, 0, 0, 0);
                }
            }

            // C: col=lane&31 -> q; row=(r&3)+8*(r>>2)+4*hi -> k_local
#pragma unroll
            for (int r = 0; r < 16; ++r) {
                const int b = (r & 3) + 8 * (r >> 2);
                if ((wsh >> b) & 1u) {
                    float s = acca[r] + accb[r];
                    if (s > bestv) { bestv = s; besti = kbase + b + 4 * hi; }
                }
            }

            if (kst == 3) {                // end of head: combine hi=0/1 halves
                float ov = __shfl_xor(bestv, 32);
                int   oi = __shfl_xor(besti, 32);
                if (ov > bestv || (ov == bestv && oi < besti)) { bestv = ov; besti = oi; }
                if (hi == 0) {
                    size_t o = ((size_t)h * KSPLIT + ks) * NPT + q;
                    pval[o] = bestv; pidx[o] = besti;
                }
            }
        }
    }
}

// ---------------------------------------------------------------------------
// 5) reduce k-split partials, gather winner V row * (1/NH)
// ---------------------------------------------------------------------------
__global__ __launch_bounds__(128) void gather_out(const float* __restrict__ V,
                                                  const float* __restrict__ pval,
                                                  const int* __restrict__ pidx,
                                                  float* __restrict__ out) {
    const int q = blockIdx.x;
    const int tid = threadIdx.x;
    __shared__ int widx[NH];
    if (tid < NH) {
        float bv = -FLT_MAX; int bi = 0;
        for (int ks = 0; ks < KSPLIT; ++ks) {
            size_t off = ((size_t)tid * KSPLIT + ks) * NPT + q;
            float v = pval[off];
            if (v > bv) { bv = v; bi = pidx[off]; }
        }
        widx[tid] = bi;
    }
    __syncthreads();
    const int h = tid >> 4;
    const int d4 = (tid & 15) * 4;
    const int k = widx[h];
    float4 v = *(const float4*)(V + (size_t)k * EMB + h * HD + d4);
    v.x *= 0.125f; v.y *= 0.125f; v.z *= 0.125f; v.w *= 0.125f;
    *(float4*)(out + (size_t)q * EMB + h * HD + d4) = v;
}

// ---------------------------------------------------------------------------
extern "C" void kernel_launch(void* const* d_in, const int* in_sizes, int n_in,
                              void* d_out, int out_size, void* d_ws, size_t ws_size,
                              hipStream_t stream) {
    const float* x   = (const float*)d_in[0];
    const int*   adj = (const int*)d_in[1];
    const float* WQ  = (const float*)d_in[2];
    const float* WK  = (const float*)d_in[3];
    const float* WV  = (const float*)d_in[4];
    // we/be are dead: energy is constant along k -> argmax unchanged.
    float* out = (float*)d_out;

    char* ws = (char*)d_ws;
    const size_t HMB = 512u * 1024;
    unsigned short* xs   = (unsigned short*)(ws);                 // 12 MB (dead after gemm)
    unsigned short* wqs  = (unsigned short*)(ws + 24 * HMB);
    unsigned short* wks  = (unsigned short*)(ws + 27 * HMB);
    unsigned short* wvs  = (unsigned short*)(ws + 30 * HMB);
    unsigned short* Q3   = (unsigned short*)(ws + 33 * HMB);      // 12 MB flat
    unsigned short* K3   = (unsigned short*)(ws + 57 * HMB);      // 12 MB granule-major
    float*          V    = (float*)(ws + 81 * HMB);               // 8 MB
    unsigned*       bits = (unsigned*)(ws + 97 * HMB);            // 2 MB
    float*          pval = (float*)(ws);                          // 4 MB, aliases dead xs
    int*            pidx = (int*)(ws + 8 * HMB);                  // 4 MB, aliases dead xs

    pack_adj_kernel<<<dim3(NPT * 128 / 256), dim3(256), 0, stream>>>(adj, bits);
    split_planes<<<dim3(2048, 4), dim3(256), 0, stream>>>(x, WQ, WK, WV, xs, wqs, wks, wvs);
    gemm_mfma<<<dim3(NPT / 128, NH, 3), dim3(256), 0, stream>>>(xs, wqs, wks, wvs, Q3, K3, V);
    score_mfma<<<dim3(NPT / 64, KSPLIT), dim3(128), 0, stream>>>(Q3, K3, bits, pval, pidx);
    gather_out<<<dim3(NPT), dim3(128), 0, stream>>>(V, pval, pidx, out);
}

// Round 10
// 276.243 us; speedup vs baseline: 1.1610x; 1.1610x over previous
//
#include <hip/hip_runtime.h>
#include <hip/hip_bf16.h>
#include <float.h>
#include <stdint.h>

#define NPT    4096
#define EMB    512
#define NH     8
#define HD     64
#define KSPLIT 32     // score k-range split: KRANGE = 128 (4 tiles of 32)

typedef __attribute__((ext_vector_type(8))) short bf16x8;
typedef __attribute__((ext_vector_type(4))) float f32x4;
typedef uint32_t u32;

// async global->LDS DMA, 16B/lane. LDS dest = wave-uniform base + lane*16.
__device__ __forceinline__ void async_ld16(const void* gsrc, void* ldst) {
    __builtin_amdgcn_global_load_lds(
        (const __attribute__((address_space(1))) u32*)gsrc,
        (__attribute__((address_space(3))) u32*)ldst, 16, 0, 0);
}

// exact 3-way bf16 split of f32 (hi+mid+lo covers all 24 mantissa bits)
__device__ __forceinline__ void split3(float a, unsigned short& h,
                                       unsigned short& m, unsigned short& l) {
    __hip_bfloat16 bh = __float2bfloat16(a);
    float fh = __bfloat162float(bh);
    float r1 = a - fh;
    __hip_bfloat16 bm = __float2bfloat16(r1);
    float fm = __bfloat162float(bm);
    float r2 = r1 - fm;
    __hip_bfloat16 bl = __float2bfloat16(r2);
    h = *reinterpret_cast<unsigned short*>(&bh);
    m = *reinterpret_cast<unsigned short*>(&bm);
    l = *reinterpret_cast<unsigned short*>(&bl);
}

// ---------------------------------------------------------------------------
// 1) fused prep: y=0 split x; y=1..3 split W (granule-major); y=4 pack adj
//    into TRANSPOSED bitmask bits_t[kword(128)][q(4096)] (coalesced score reads)
// ---------------------------------------------------------------------------
__global__ __launch_bounds__(256) void prep_kernel(const float* __restrict__ x,
                                                   const float* __restrict__ wq,
                                                   const float* __restrict__ wk,
                                                   const float* __restrict__ wv,
                                                   const int* __restrict__ adj,
                                                   unsigned short* __restrict__ xs,
                                                   unsigned short* __restrict__ wqs,
                                                   unsigned short* __restrict__ wks,
                                                   unsigned short* __restrict__ wvs,
                                                   unsigned* __restrict__ bits_t) {
    int y = blockIdx.y;
    size_t i = (size_t)blockIdx.x * 256 + threadIdx.x;
    if (y == 4) {                               // pack adj (reads coalesced)
        int q = (int)(i >> 7), w = (int)i & 127;
        const int4* p = (const int4*)(adj + (size_t)q * NPT + w * 32);
        unsigned m = 0;
#pragma unroll
        for (int j = 0; j < 8; ++j) {
            int4 v = p[j];
            m |= (v.x != 0 ? 1u : 0u) << (j * 4 + 0);
            m |= (v.y != 0 ? 1u : 0u) << (j * 4 + 1);
            m |= (v.z != 0 ? 1u : 0u) << (j * 4 + 2);
            m |= (v.w != 0 ? 1u : 0u) << (j * 4 + 3);
        }
        bits_t[(size_t)w * NPT + q] = m;        // transposed write (2 MB, cheap)
    } else if (y == 0) {
        const size_t PL = (size_t)NPT * EMB;
        float4 v = ((const float4*)x)[i];
        ushort4 h, m, l;
        split3(v.x, h.x, m.x, l.x);
        split3(v.y, h.y, m.y, l.y);
        split3(v.z, h.z, m.z, l.z);
        split3(v.w, h.w, m.w, l.w);
        ((ushort4*)xs)[i]            = h;
        ((ushort4*)(xs + PL))[i]     = m;
        ((ushort4*)(xs + 2 * PL))[i] = l;
    } else {
        const size_t WPL = 262144;
        if (i >= WPL / 4) return;
        const float* src = (y == 1) ? wq : (y == 2) ? wk : wv;
        unsigned short* dst = (y == 1) ? wqs : (y == 2) ? wks : wvs;
        float4 v = ((const float4*)src)[i];
        int e  = (int)(i >> 7);
        int k0 = ((int)i & 127) * 4;
        int ebk = e >> 6, el = e & 63;
        int kc = k0 >> 5, g = (k0 >> 3) & 3, dd = k0 & 7;
        size_t off = ((((size_t)ebk * 16 + kc) * 4 + g) * 64 + el) * 8 + dd;
        ushort4 h, m, l;
        split3(v.x, h.x, m.x, l.x);
        split3(v.y, h.y, m.y, l.y);
        split3(v.z, h.z, m.z, l.z);
        split3(v.w, h.w, m.w, l.w);
        *(ushort4*)(dst + off)           = h;
        *(ushort4*)(dst + WPL + off)     = m;
        *(ushort4*)(dst + 2 * WPL + off) = l;
    }
}

// ---------------------------------------------------------------------------
// 2) projections via split-bf16 MFMA (R8 structure). Q3 AND K3 now both
//    granule-major: [p][h][t32(128)][dg(8)][i32(32)][8shorts]
// ---------------------------------------------------------------------------
__global__ __launch_bounds__(256) void gemm_mfma(const unsigned short* __restrict__ xs,
                                                 const unsigned short* __restrict__ wqs,
                                                 const unsigned short* __restrict__ wks,
                                                 const unsigned short* __restrict__ wvs,
                                                 unsigned short* __restrict__ Q3,
                                                 unsigned short* __restrict__ K3,
                                                 float* __restrict__ V) {
    const int z = blockIdx.z;
    const unsigned short* W3 = (z == 0) ? wqs : (z == 1) ? wks : wvs;
    const size_t XPL = (size_t)NPT * EMB;
    const size_t WPL = 262144;
    const size_t OPL = (size_t)NH * NPT * HD;

    const int nb = blockIdx.x * 128;
    const int ebk = blockIdx.y;
    const int tid = threadIdx.x;
    const int wv = tid >> 6, lane = tid & 63;
    const int m = lane & 15, quad = lane >> 4;
    const int n0 = nb + wv * 32;

    __shared__ __align__(16) unsigned short Ws[2][3 * 2048];

    auto prefetchW = [&](int kc, int buf) {
#pragma unroll
        for (int i2 = 0; i2 < 3; ++i2) {
            int c = wv + 4 * i2;
            int p = c >> 2, sub = c & 3;
            const unsigned short* src = W3 + (size_t)p * WPL
                + ((size_t)ebk * 16 + kc) * 2048 + (sub * 64 + lane) * 8;
            async_ld16(src, &Ws[buf][p * 2048 + sub * 512]);
        }
    };
    bf16x8 bfA[2][3], bfB[2][3];
    auto load_bf = [&](bf16x8 (&bf)[2][3], int kc) {
#pragma unroll
        for (int nt = 0; nt < 2; ++nt)
#pragma unroll
            for (int p = 0; p < 3; ++p)
                bf[nt][p] = *(const bf16x8*)(xs + (size_t)p * XPL
                    + (size_t)(n0 + nt * 16 + m) * EMB + kc * 32 + quad * 8);
    };

    f32x4 acc[4][2];
#pragma unroll
    for (int mt = 0; mt < 4; ++mt)
#pragma unroll
        for (int nt = 0; nt < 2; ++nt) acc[mt][nt] = (f32x4){0.f, 0.f, 0.f, 0.f};

    prefetchW(0, 0);
    load_bf(bfA, 0);

    auto iter = [&](int kc, int buf, bf16x8 (&cur)[2][3], bf16x8 (&nxt)[2][3]) {
        __syncthreads();
        if (kc < 15) { prefetchW(kc + 1, buf ^ 1); load_bf(nxt, kc + 1); }
#pragma unroll
        for (int ga = 0; ga < 3; ++ga) {
            bf16x8 af[4];
#pragma unroll
            for (int mt = 0; mt < 4; ++mt)
                af[mt] = *(const bf16x8*)&Ws[buf][ga * 2048 + (quad * 64 + mt * 16 + m) * 8];
#pragma unroll
            for (int pb = 0; pb < 3 - ga; ++pb)
#pragma unroll
                for (int mt = 0; mt < 4; ++mt)
#pragma unroll
                    for (int nt = 0; nt < 2; ++nt)
                        acc[mt][nt] = __builtin_amdgcn_mfma_f32_16x16x32_bf16(
                            af[mt], cur[nt][pb], acc[mt][nt], 0, 0, 0);
        }
    };

#pragma unroll 1
    for (int kc2 = 0; kc2 < 16; kc2 += 2) {
        iter(kc2, 0, bfA, bfB);
        iter(kc2 + 1, 1, bfB, bfA);
    }

    const int h = ebk;
#pragma unroll
    for (int mt = 0; mt < 4; ++mt)
#pragma unroll
        for (int nt = 0; nt < 2; ++nt) {
            const int n = n0 + nt * 16 + m;
            const int d0 = mt * 16 + quad * 4;
            f32x4 a = acc[mt][nt];
            if (z == 2) {
                *(f32x4*)(V + (size_t)n * EMB + ebk * 64 + d0) = a;
            } else {
                ushort4 ph, pm, pl;
                split3(a[0], ph.x, pm.x, pl.x);
                split3(a[1], ph.y, pm.y, pl.y);
                split3(a[2], ph.z, pm.z, pl.z);
                split3(a[3], ph.w, pm.w, pl.w);
                // granule-major: [t32][dg][i32][8]
                unsigned short* O3 = (z == 0) ? Q3 : K3;
                size_t off = ((size_t)h * 128 + (n >> 5)) * 2048
                           + (d0 >> 3) * 256 + (n & 31) * 8 + (d0 & 7);
                *(ushort4*)(O3 + off)           = ph;
                *(ushort4*)(O3 + OPL + off)     = pm;
                *(ushort4*)(O3 + 2 * OPL + off) = pl;
            }
        }
}

// ---------------------------------------------------------------------------
// 3) masked argmax via bf16x3 MFMA, 16x16x32 (R8 base). Triple-buffered K
//    tiles via global_load_lds with MANUAL s_waitcnt vmcnt(3)+s_barrier
//    (prefetch distance 2; never drains the in-flight tile). Q3 granule-major
//    -> coalesced qf; bits_t transposed -> coalesced mask loads.
// ---------------------------------------------------------------------------
__global__ __launch_bounds__(256) void score_mfma(const unsigned short* __restrict__ Q3,
                                                  const unsigned short* __restrict__ K3,
                                                  const unsigned* __restrict__ bits_t,
                                                  float* __restrict__ pval,
                                                  int* __restrict__ pidx) {
    const int qb = blockIdx.x * 128;
    const int ks = blockIdx.y;
    const int tid = threadIdx.x;
    const int wv = tid >> 6, lane = tid & 63;
    const int m = lane & 15, quad = lane >> 4;
    const size_t PL = (size_t)NH * NPT * HD;
    const int kq = qb + wv * 32;

    __shared__ __align__(16) unsigned short Ks[3][3 * 2048];   // 3 x 12 KB

    auto prefetchK = [&](int t) {          // 3 DMA chunks per wave per tile
        int h = t >> 2, kt = ks * 4 + (t & 3), buf = t % 3;
#pragma unroll
        for (int i2 = 0; i2 < 3; ++i2) {
            int c = wv + 4 * i2;
            int p = c >> 2, sub = c & 3;
            const unsigned short* src = K3 + (size_t)p * PL
                + ((size_t)h * 128 + kt) * 2048 + (sub * 64 + lane) * 8;
            async_ld16(src, &Ks[buf][p * 2048 + sub * 512]);
        }
    };

    prefetchK(0);
    prefetchK(1);

    bf16x8 qf[2][2][3];
    float bestv[2]; int besti[2];

#pragma unroll 1
    for (int t = 0; t < NH * 4; ++t) {
        const int h = t >> 2, kst = t & 3, buf = t % 3;
        const int kbase = ks * 128 + kst * 32;

        // wait own 3 chunks of tile t (issued at t-2); tile t+1's 3 stay in
        // flight. Barrier WITHOUT the compiler's vmcnt(0) drain.
        asm volatile("s_waitcnt vmcnt(3)\n\ts_barrier" ::: "memory");

        if (kst == 0) {                    // coalesced qf from granule-major Q3
#pragma unroll
            for (int nt = 0; nt < 2; ++nt)
#pragma unroll
                for (int dc = 0; dc < 2; ++dc)
#pragma unroll
                    for (int p = 0; p < 3; ++p)
                        qf[nt][dc][p] = *(const bf16x8*)(Q3 + (size_t)p * PL
                            + ((size_t)h * 128 + (kq >> 5)) * 2048
                            + (dc * 4 + quad) * 256 + (nt * 16 + m) * 8);
            bestv[0] = bestv[1] = -FLT_MAX;
            besti[0] = besti[1] = 0;
        }

        unsigned bw[2];                    // coalesced: lanes -> consecutive q
#pragma unroll
        for (int nt = 0; nt < 2; ++nt)
            bw[nt] = bits_t[(size_t)(ks * 4 + kst) * NPT + kq + nt * 16 + m];

        if (t + 2 < NH * 4) prefetchK(t + 2);   // youngest loads (after qf/bits)

        f32x4 acc[2][2];
#pragma unroll
        for (int mt = 0; mt < 2; ++mt)
#pragma unroll
            for (int nt = 0; nt < 2; ++nt) acc[mt][nt] = (f32x4){0.f, 0.f, 0.f, 0.f};

#pragma unroll
        for (int ga = 0; ga < 3; ++ga) {
            bf16x8 kf[2][2];
#pragma unroll
            for (int mt = 0; mt < 2; ++mt)
#pragma unroll
                for (int dc = 0; dc < 2; ++dc)
                    kf[mt][dc] = *(const bf16x8*)
                        &Ks[buf][ga * 2048 + ((dc * 4 + quad) * 32 + mt * 16 + m) * 8];
#pragma unroll
            for (int pb = 0; pb < 3 - ga; ++pb)
#pragma unroll
                for (int dc = 0; dc < 2; ++dc)
#pragma unroll
                    for (int mt = 0; mt < 2; ++mt)
#pragma unroll
                        for (int nt = 0; nt < 2; ++nt)
                            acc[mt][nt] = __builtin_amdgcn_mfma_f32_16x16x32_bf16(
                                kf[mt][dc], qf[nt][dc][pb], acc[mt][nt], 0, 0, 0);
        }

        // C: col=lane&15 -> q; row=quad*4+r -> k
#pragma unroll
        for (int nt = 0; nt < 2; ++nt) {
            unsigned w = bw[nt];
#pragma unroll
            for (int mt = 0; mt < 2; ++mt) {
                int k0 = mt * 16 + quad * 4;
                f32x4 a = acc[mt][nt];
#pragma unroll
                for (int r = 0; r < 4; ++r) {
                    if ((w >> (k0 + r)) & 1u) {
                        float s = a[r];
                        if (s > bestv[nt]) { bestv[nt] = s; besti[nt] = kbase + k0 + r; }
                    }
                }
            }
        }

        if (kst == 3) {                    // end of head: reduce over quad groups
#pragma unroll
            for (int nt = 0; nt < 2; ++nt) {
                float v = bestv[nt]; int bi = besti[nt];
#pragma unroll
                for (int off = 16; off < 64; off <<= 1) {
                    float ov = __shfl_xor(v, off);
                    int   oi = __shfl_xor(bi, off);
                    if (ov > v || (ov == v && oi < bi)) { v = ov; bi = oi; }
                }
                if (quad == 0) {
                    size_t o = ((size_t)h * KSPLIT + ks) * NPT + kq + nt * 16 + m;
                    pval[o] = v; pidx[o] = bi;
                }
            }
        }
    }
}

// ---------------------------------------------------------------------------
// 4) reduce k-split partials, gather winner V row * (1/NH)
// ---------------------------------------------------------------------------
__global__ __launch_bounds__(128) void gather_out(const float* __restrict__ V,
                                                  const float* __restrict__ pval,
                                                  const int* __restrict__ pidx,
                                                  float* __restrict__ out) {
    const int q = blockIdx.x;
    const int tid = threadIdx.x;
    __shared__ int widx[NH];
    if (tid < NH) {
        float bv = -FLT_MAX; int bi = 0;
        for (int ks = 0; ks < KSPLIT; ++ks) {
            size_t off = ((size_t)tid * KSPLIT + ks) * NPT + q;
            float v = pval[off];
            if (v > bv) { bv = v; bi = pidx[off]; }
        }
        widx[tid] = bi;
    }
    __syncthreads();
    const int h = tid >> 4;
    const int d4 = (tid & 15) * 4;
    const int k = widx[h];
    float4 v = *(const float4*)(V + (size_t)k * EMB + h * HD + d4);
    v.x *= 0.125f; v.y *= 0.125f; v.z *= 0.125f; v.w *= 0.125f;
    *(float4*)(out + (size_t)q * EMB + h * HD + d4) = v;
}

// ---------------------------------------------------------------------------
extern "C" void kernel_launch(void* const* d_in, const int* in_sizes, int n_in,
                              void* d_out, int out_size, void* d_ws, size_t ws_size,
                              hipStream_t stream) {
    const float* x   = (const float*)d_in[0];
    const int*   adj = (const int*)d_in[1];
    const float* WQ  = (const float*)d_in[2];
    const float* WK  = (const float*)d_in[3];
    const float* WV  = (const float*)d_in[4];
    // we/be are dead: energy is constant along k -> argmax unchanged.
    float* out = (float*)d_out;

    char* ws = (char*)d_ws;
    const size_t HMB = 512u * 1024;
    unsigned short* xs   = (unsigned short*)(ws);                 // 12 MB (dead after gemm)
    unsigned short* wqs  = (unsigned short*)(ws + 24 * HMB);
    unsigned short* wks  = (unsigned short*)(ws + 27 * HMB);
    unsigned short* wvs  = (unsigned short*)(ws + 30 * HMB);
    unsigned short* Q3   = (unsigned short*)(ws + 33 * HMB);      // 12 MB granule-major
    unsigned short* K3   = (unsigned short*)(ws + 57 * HMB);      // 12 MB granule-major
    float*          V    = (float*)(ws + 81 * HMB);               // 8 MB
    unsigned*       bits = (unsigned*)(ws + 97 * HMB);            // 2 MB transposed
    float*          pval = (float*)(ws);                          // 4 MB, aliases dead xs
    int*            pidx = (int*)(ws + 8 * HMB);                  // 4 MB, aliases dead xs

    prep_kernel<<<dim3(2048, 5), dim3(256), 0, stream>>>(x, WQ, WK, WV, adj,
                                                         xs, wqs, wks, wvs, bits);
    gemm_mfma<<<dim3(NPT / 128, NH, 3), dim3(256), 0, stream>>>(xs, wqs, wks, wvs, Q3, K3, V);
    score_mfma<<<dim3(NPT / 128, KSPLIT), dim3(256), 0, stream>>>(Q3, K3, bits, pval, pidx);
    gather_out<<<dim3(NPT), dim3(128), 0, stream>>>(V, pval, pidx, out);
}